// Round 1
// baseline (1785.368 us; speedup 1.0000x reference)
//
#include <hip/hip_runtime.h>
#include <hip/hip_bf16.h>
#include <stdint.h>

// Problem constants (B,S,H,L) = (8, 4096, 2048, 4)
#define B_ 8
#define S_ 4096
#define H_ 2048
#define L_ 4
#define M_ (B_ * S_)   // 32768 rows
// GEMM: C[M,N] = A[M,K] * W[N,K]^T + bias, K = N = H_

typedef __bf16 bf16_t;
typedef __attribute__((ext_vector_type(8))) __bf16 bf16x8;
typedef __attribute__((ext_vector_type(4))) float f32x4;

__device__ __forceinline__ unsigned short f32_bf16_rne(float f) {
    union { float f; unsigned int u; } v;
    v.f = f;
    unsigned int u = v.u;
    u += 0x7FFFu + ((u >> 16) & 1u);   // round-to-nearest-even
    return (unsigned short)(u >> 16);
}

__global__ void cvt_f32_to_bf16(const float4* __restrict__ in,
                                ushort4* __restrict__ out, int n4) {
    int i = blockIdx.x * blockDim.x + threadIdx.x;
    if (i < n4) {
        float4 v = in[i];
        ushort4 o;
        o.x = f32_bf16_rne(v.x);
        o.y = f32_bf16_rne(v.y);
        o.z = f32_bf16_rne(v.z);
        o.w = f32_bf16_rne(v.w);
        out[i] = o;
    }
}

// m97-style 128x128-tile bf16 GEMM, B^T layout, global_load_lds(16B) staging.
// A-row gather via perm (perm==nullptr -> identity). Bias fused in epilogue.
// OUT_BF16=true -> bf16 intermediate store; false -> fp32 final store.
template <bool OUT_BF16>
__global__ __launch_bounds__(256, 2)
void gemm_bt(const unsigned short* __restrict__ A,   // M x K, bf16 bits
             const unsigned short* __restrict__ W,   // N x K, bf16 bits
             const float* __restrict__ bias,         // N
             const int* __restrict__ perm,           // S_ entries or nullptr
             void* __restrict__ outv)                // M x N
{
    constexpr int K = H_;
    constexpr int N = H_;

    __shared__ unsigned short smA[128 * 64];  // 16 KB: 128 rows x 64 k (bf16)
    __shared__ unsigned short smB[128 * 64];  // 16 KB

    const int t = threadIdx.x;
    const int w = t >> 6;     // wave 0..3
    const int l = t & 63;     // lane
    const int tile_m = blockIdx.y;
    const int tile_n = blockIdx.x;

    // ---- staging assignment: per issue 'it', wave w covers rows it*32+w*8 .. +8,
    // lane l -> row sub l>>3, 16B chunk l&7. LDS dest = uniform base + lane*16B.
    const int chunk = l & 7;
    const int rsub  = l >> 3;

    const unsigned short* aSrc[4];
    const unsigned short* bSrc[4];
    const unsigned short* ldsA[4];
    const unsigned short* ldsB[4];
#pragma unroll
    for (int it = 0; it < 4; ++it) {
        int r  = it * 32 + w * 8 + rsub;          // 0..127 within tile
        int gm = tile_m * 128 + r;                // logical output row
        int src;
        if (perm) {
            int b = gm >> 12;                     // / S_ (4096)
            int s = gm & (S_ - 1);
            src = (b << 12) + perm[s];            // gather source row
        } else {
            src = gm;
        }
        aSrc[it] = A + (size_t)src * K + chunk * 8;
        bSrc[it] = W + (size_t)(tile_n * 128 + r) * K + chunk * 8;
        ldsA[it] = &smA[(it * 32 + w * 8) * 64];  // wave-uniform base
        ldsB[it] = &smB[(it * 32 + w * 8) * 64];
    }

    // ---- compute assignment: 2x2 waves, each wave 64x64 = 4x4 MFMA 16x16 tiles
    const int wm   = w & 1;
    const int wn   = w >> 1;
    const int lm   = l & 15;   // A row / B col within 16-tile
    const int quad = l >> 4;   // 0..3, k-octet selector

    const unsigned short* fragA_base = &smA[(wm * 64 + lm) * 64 + quad * 8];
    const unsigned short* fragB_base = &smB[(wn * 64 + lm) * 64 + quad * 8];

    f32x4 acc[4][4];
#pragma unroll
    for (int i = 0; i < 4; ++i)
#pragma unroll
        for (int j = 0; j < 4; ++j) {
            f32x4 z = {0.f, 0.f, 0.f, 0.f};
            acc[i][j] = z;
        }

    for (int k0 = 0; k0 < K; k0 += 64) {
#pragma unroll
        for (int it = 0; it < 4; ++it) {
            __builtin_amdgcn_global_load_lds(
                (const __attribute__((address_space(1))) void*)(aSrc[it] + k0),
                (__attribute__((address_space(3))) void*)(ldsA[it]), 16, 0, 0);
            __builtin_amdgcn_global_load_lds(
                (const __attribute__((address_space(1))) void*)(bSrc[it] + k0),
                (__attribute__((address_space(3))) void*)(ldsB[it]), 16, 0, 0);
        }
        __syncthreads();   // drains vmcnt -> LDS tiles valid

#pragma unroll
        for (int ks = 0; ks < 2; ++ks) {
            bf16x8 af[4], bf[4];
#pragma unroll
            for (int i = 0; i < 4; ++i)
                af[i] = *(const bf16x8*)(fragA_base + i * 16 * 64 + ks * 32);
#pragma unroll
            for (int j = 0; j < 4; ++j)
                bf[j] = *(const bf16x8*)(fragB_base + j * 16 * 64 + ks * 32);
#pragma unroll
            for (int i = 0; i < 4; ++i)
#pragma unroll
                for (int j = 0; j < 4; ++j)
                    acc[i][j] = __builtin_amdgcn_mfma_f32_16x16x32_bf16(
                        af[i], bf[j], acc[i][j], 0, 0, 0);
        }
        __syncthreads();   // compute done before next stage overwrites LDS
    }

    // ---- epilogue: C/D layout col = lane&15, row = quad*4 + reg (m89/m91)
    const int orow0 = tile_m * 128 + wm * 64 + quad * 4;
    const int ocol0 = tile_n * 128 + wn * 64 + lm;
    float bval[4];
#pragma unroll
    for (int j = 0; j < 4; ++j) bval[j] = bias[ocol0 + j * 16];

#pragma unroll
    for (int i = 0; i < 4; ++i) {
#pragma unroll
        for (int j = 0; j < 4; ++j) {
#pragma unroll
            for (int r = 0; r < 4; ++r) {
                int row = orow0 + i * 16 + r;
                int col = ocol0 + j * 16;
                float v = acc[i][j][r] + bval[j];
                if (OUT_BF16) {
                    ((unsigned short*)outv)[(size_t)row * N + col] = f32_bf16_rne(v);
                } else {
                    ((float*)outv)[(size_t)row * N + col] = v;
                }
            }
        }
    }
}

extern "C" void kernel_launch(void* const* d_in, const int* in_sizes, int n_in,
                              void* d_out, int out_size, void* d_ws, size_t ws_size,
                              hipStream_t stream) {
    const float* x       = (const float*)d_in[0];  // (8,4096,2048) f32
    const float* weights = (const float*)d_in[1];  // (4,2048,2048) f32
    const float* biases  = (const float*)d_in[2];  // (4,2048) f32
    const int*   perms   = (const int*)d_in[3];    // (3,4096) i32
    float* out = (float*)d_out;

    // ws layout: P = bf16 ping buffer (128 MB), Wbf = bf16 weights (32 MB).
    // Q = low half of d_out reinterpreted as bf16 (d_out is 256 MB fp32).
    // Sequence Q -> P -> Q -> P -> d_out keeps final-layer input (P) disjoint
    // from its fp32 output (d_out).
    unsigned short* bufP = (unsigned short*)d_ws;
    unsigned short* wBf  = (unsigned short*)((char*)d_ws + (size_t)M_ * H_ * 2);
    unsigned short* bufQ = (unsigned short*)d_out;

    {
        int n4 = (L_ * H_ * H_) / 4;
        cvt_f32_to_bf16<<<(n4 + 255) / 256, 256, 0, stream>>>(
            (const float4*)weights, (ushort4*)wBf, n4);
    }
    {
        int n4 = (M_ * H_) / 4;
        cvt_f32_to_bf16<<<(n4 + 255) / 256, 256, 0, stream>>>(
            (const float4*)x, (ushort4*)bufQ, n4);
    }

    dim3 grid(H_ / 128, M_ / 128);  // (16, 256)
    // layer 0: no gather
    gemm_bt<true ><<<grid, 256, 0, stream>>>(bufQ, wBf + 0 * H_ * H_,
                                             biases + 0 * H_, nullptr, bufP);
    // layer 1: gather rows via perms[0]
    gemm_bt<true ><<<grid, 256, 0, stream>>>(bufP, wBf + 1 * H_ * H_,
                                             biases + 1 * H_, perms + 0 * S_, bufQ);
    // layer 2: gather via perms[1]
    gemm_bt<true ><<<grid, 256, 0, stream>>>(bufQ, wBf + 2 * H_ * H_,
                                             biases + 2 * H_, perms + 1 * S_, bufP);
    // layer 3: gather via perms[2], fp32 output
    gemm_bt<false><<<grid, 256, 0, stream>>>(bufP, wBf + 3 * H_ * H_,
                                             biases + 3 * H_, perms + 2 * S_, out);
}